// Round 1
// baseline (164.642 us; speedup 1.0000x reference)
//
#include <hip/hip_runtime.h>

#define NREL 32

// ---------------------------------------------------------------------------
// ws layout (floats):
//   wnf  [32*4096]  normalized fwd weight tables
//   wnb  [32*4096]  normalized bwd weight tables
//   cntf [N]        # edges with src==n   (fwd degree source)
//   cntb [N]        # edges with dst==n   (bwd degree source)
//   lwT  [4096]     lin_w transposed: lwT[i*64+o] = lin_w[o*64+i]
// ---------------------------------------------------------------------------

__global__ void count_kernel(const int* __restrict__ src, const int* __restrict__ dst,
                             float* __restrict__ cntf, float* __restrict__ cntb, int E) {
    int e = blockIdx.x * blockDim.x + threadIdx.x;
    if (e < E) {
        atomicAdd(&cntf[src[e]], 1.0f);
        atomicAdd(&cntb[dst[e]], 1.0f);
    }
}

// One block per (table, rel): 64 blocks x 256 threads. Each rel row is 4096 floats.
__global__ void norm_kernel(const float* __restrict__ wf, const float* __restrict__ wb,
                            float* __restrict__ wnf, float* __restrict__ wnb) {
    int rel = blockIdx.x & 31;
    int tab = blockIdx.x >> 5;
    const float* s_ = (tab ? wb : wf) + rel * 4096;
    float*       d_ = (tab ? wnb : wnf) + rel * 4096;
    int tid = threadIdx.x;

    float ssum = 0.f;
    #pragma unroll
    for (int k = 0; k < 16; k += 4) {
        float4 v = *(const float4*)(s_ + tid * 16 + k);
        ssum += v.x * v.x + v.y * v.y + v.z * v.z + v.w * v.w;
    }
    // wave64 reduce
    #pragma unroll
    for (int off = 32; off >= 1; off >>= 1) ssum += __shfl_down(ssum, off, 64);

    __shared__ float part[4];
    __shared__ float scale_s;
    int wslot = tid >> 6;
    if ((tid & 63) == 0) part[wslot] = ssum;
    __syncthreads();
    if (tid == 0) {
        float tot = part[0] + part[1] + part[2] + part[3];
        scale_s = 1.0f / (sqrtf(tot) + 0.01f);
    }
    __syncthreads();
    float sc = scale_s;
    #pragma unroll
    for (int k = 0; k < 16; k += 4) {
        float4 v = *(const float4*)(s_ + tid * 16 + k);
        v.x *= sc; v.y *= sc; v.z *= sc; v.w *= sc;
        *(float4*)(d_ + tid * 16 + k) = v;
    }
}

__global__ void transpose_lw(const float* __restrict__ lw, float* __restrict__ lwT) {
    int t = threadIdx.x; // 256 threads, 16 elems each
    for (int k = t * 16; k < t * 16 + 16; ++k) {
        int o = k & 63, i = k >> 6;       // k = i*64 + o
        lwT[k] = lw[o * 64 + i];
    }
}

// out[n,o] = lin_b[o] + sum_i x[n,i] * lin_w[o,i]   (one wave per node)
__global__ void linear_kernel(const float* __restrict__ x, const float* __restrict__ lwT,
                              const float* __restrict__ lb, float* __restrict__ out, int N) {
    __shared__ float xs[4][64];
    int lane  = threadIdx.x & 63;
    int wslot = threadIdx.x >> 6;
    int n = blockIdx.x * 4 + wslot;
    bool valid = (n < N);
    int nn = valid ? n : 0;

    xs[wslot][lane] = x[nn * 64 + lane];
    __syncthreads();

    float acc = lb[lane];
    #pragma unroll
    for (int i = 0; i < 64; i += 4) {
        float4 xi = *(const float4*)(&xs[wslot][i]);
        acc = fmaf(xi.x, lwT[(i + 0) * 64 + lane], acc);
        acc = fmaf(xi.y, lwT[(i + 1) * 64 + lane], acc);
        acc = fmaf(xi.z, lwT[(i + 2) * 64 + lane], acc);
        acc = fmaf(xi.w, lwT[(i + 3) * 64 + lane], acc);
    }
    if (valid) out[n * 64 + lane] = acc;
}

// One wave per (edge, direction). Lane o computes output channel o.
// msg = (x[s]/deg[s]) @ Wn[t];  atomicAdd into out[d].
__global__ void conv_kernel(const float* __restrict__ x,
                            const int* __restrict__ src, const int* __restrict__ dst,
                            const int* __restrict__ etype,
                            const float* __restrict__ wnf, const float* __restrict__ wnb,
                            const float* __restrict__ cntf, const float* __restrict__ cntb,
                            float* __restrict__ out, int E) {
    __shared__ float xs[4][64];
    int lane  = threadIdx.x & 63;
    int wslot = threadIdx.x >> 6;
    int gw = blockIdx.x * 4 + wslot;         // [0, 2E)
    bool valid = (gw < 2 * E);
    int gwc = valid ? gw : 0;
    int dir = (gwc >= E);
    int e   = dir ? gwc - E : gwc;

    int s_, d_;
    const float* wtab;
    const float* cnt;
    if (!dir) { s_ = src[e]; d_ = dst[e]; wtab = wnf; cnt = cntf; }
    else      { s_ = dst[e]; d_ = src[e]; wtab = wnb; cnt = cntb; }
    int t = etype[e];

    float invdeg = 1.0f / (cnt[s_] + 1.0f);
    xs[wslot][lane] = x[s_ * 64 + lane] * invdeg;
    __syncthreads();

    float acc = 0.f;
    const float* wr = wtab + t * 4096 + lane;  // row i stride 64 -> coalesced per i
    #pragma unroll
    for (int i = 0; i < 64; i += 4) {
        float4 xi = *(const float4*)(&xs[wslot][i]);  // broadcast read
        acc = fmaf(xi.x, wr[(i + 0) * 64], acc);
        acc = fmaf(xi.y, wr[(i + 1) * 64], acc);
        acc = fmaf(xi.z, wr[(i + 2) * 64], acc);
        acc = fmaf(xi.w, wr[(i + 3) * 64], acc);
    }
    if (valid) atomicAdd(&out[d_ * 64 + lane], acc);
}

extern "C" void kernel_launch(void* const* d_in, const int* in_sizes, int n_in,
                              void* d_out, int out_size, void* d_ws, size_t ws_size,
                              hipStream_t stream) {
    const float* x  = (const float*)d_in[0];
    const int*   ei = (const int*)  d_in[1];   // [2, E] (harness converts int64 -> int32)
    const int*   et = (const int*)  d_in[2];   // [E]
    const float* wf = (const float*)d_in[3];
    const float* wb = (const float*)d_in[4];
    const float* lw = (const float*)d_in[5];
    const float* lb = (const float*)d_in[6];
    float* out = (float*)d_out;

    const int E = in_sizes[2];
    const int N = in_sizes[0] / 64;

    float* ws   = (float*)d_ws;
    float* wnf  = ws;
    float* wnb  = wnf + NREL * 4096;
    float* cntf = wnb + NREL * 4096;
    float* cntb = cntf + N;
    float* lwT  = cntb + N;

    const int* srcp = ei;
    const int* dstp = ei + E;

    hipMemsetAsync(cntf, 0, (size_t)2 * N * sizeof(float), stream);

    count_kernel<<<(E + 255) / 256, 256, 0, stream>>>(srcp, dstp, cntf, cntb, E);
    norm_kernel<<<64, 256, 0, stream>>>(wf, wb, wnf, wnb);
    transpose_lw<<<1, 256, 0, stream>>>(lw, lwT);
    linear_kernel<<<(N + 3) / 4, 256, 0, stream>>>(x, lwT, lb, out, N);
    conv_kernel<<<(2 * E + 3) / 4, 256, 0, stream>>>(x, srcp, dstp, et,
                                                     wnf, wnb, cntf, cntb, out, E);
}